// Round 22
// baseline (544.499 us; speedup 1.0000x reference)
//
#include <hip/hip_runtime.h>
#include <hip/hip_bf16.h>
#include <math.h>

typedef __attribute__((ext_vector_type(8))) unsigned short u16x8;
typedef __attribute__((ext_vector_type(4))) unsigned short u16x4;
typedef __attribute__((ext_vector_type(8))) short bf16x8;   // MFMA A/B frag (8 bf16)
typedef __attribute__((ext_vector_type(4))) float f32x4;    // MFMA C/D frag

#define NRELMAX 32

__device__ __forceinline__ float b2f(unsigned short u) {
    return __uint_as_float(((unsigned)u) << 16);
}
__device__ __forceinline__ unsigned short f2b(float v) {
    __hip_bfloat16 b = __float2bfloat16(v);
    return *reinterpret_cast<unsigned short*>(&b);
}

// ---------- MFMA GEMM (m89-verified wiring) ----------
__device__ __forceinline__ bf16x8 lda_frag(const __hip_bfloat16* p) {
    return *(const bf16x8*)p;
}
__device__ __forceinline__ void st_o(__hip_bfloat16* p, float v) { *p = __float2bfloat16(v); }
__device__ __forceinline__ void st_o(float* p, float v) { *p = v; }

template <typename TO>
__device__ __forceinline__ void gemm_body(const __hip_bfloat16* __restrict__ A,
                                          const __hip_bfloat16* __restrict__ Wt,
                                          TO* __restrict__ out, int n, int blk)
{
    const int tid = threadIdx.x;
    const int w = tid >> 6;
    const int l = tid & 63;
    const int q = l >> 4;
    const int c16 = l & 15;
    const int wr = (w >> 1) * 64;
    const int wc = (w & 1) * 64;
    const long row0 = (long)blk * 128;

    f32x4 acc[4][4] = {};
    #pragma unroll
    for (int ks = 0; ks < 4; ++ks) {
        bf16x8 af[4];
        #pragma unroll
        for (int rb = 0; rb < 4; ++rb) {
            long r = row0 + wr + rb * 16 + c16;
            if (r >= n) r = n - 1;
            af[rb] = lda_frag(A + r * 128 + ks * 32 + q * 8);
        }
        #pragma unroll
        for (int cb = 0; cb < 4; ++cb) {
            bf16x8 wf = *(const bf16x8*)(Wt + (size_t)(wc + cb * 16 + c16) * 128 + ks * 32 + q * 8);
            #pragma unroll
            for (int rb = 0; rb < 4; ++rb)
                acc[rb][cb] = __builtin_amdgcn_mfma_f32_16x16x32_bf16(af[rb], wf, acc[rb][cb], 0, 0, 0);
        }
    }
    #pragma unroll
    for (int rb = 0; rb < 4; ++rb) {
        #pragma unroll
        for (int r = 0; r < 4; ++r) {
            long row = row0 + wr + rb * 16 + q * 4 + r;
            if (row < n) {
                #pragma unroll
                for (int cb = 0; cb < 4; ++cb)
                    st_o(out + row * 128 + wc + cb * 16 + c16, acc[rb][cb][r]);
            }
        }
    }
}

template <typename TO>
__global__ __launch_bounds__(256) void mfma_gemm(const __hip_bfloat16* __restrict__ A,
                                                 const __hip_bfloat16* __restrict__ Wt,
                                                 TO* __restrict__ out, int n)
{
    gemm_body<TO>(A, Wt, out, n, blockIdx.x);
}

// ---------- prep: trans_w | conv_tab | conv_emb (streaming) ----------
__global__ __launch_bounds__(256) void prep(
    const float* __restrict__ W0, const float* __restrict__ W1,
    const float* __restrict__ W2, const float* __restrict__ W3,
    __hip_bfloat16* __restrict__ T0, __hip_bfloat16* __restrict__ T1,
    __hip_bfloat16* __restrict__ T2, __hip_bfloat16* __restrict__ T3,
    const float* __restrict__ att, const float* __restrict__ msg,
    __hip_bfloat16* __restrict__ Atab, __hip_bfloat16* __restrict__ Mtab, int nrel,
    const float* __restrict__ emb, __hip_bfloat16* __restrict__ embb, long n4,
    int nbW, int nbT)
{
    const int tid = threadIdx.x;
    const int bx = blockIdx.x;
    if (bx < nbW) {
        int t = bx * 256 + tid;
        int w = t >> 14, r = t & 16383;
        const float* W = (w == 0) ? W0 : (w == 1) ? W1 : (w == 2) ? W2 : W3;
        __hip_bfloat16* T = (w == 0) ? T0 : (w == 1) ? T1 : (w == 2) ? T2 : T3;
        int k = r >> 7, c = r & 127;
        T[(size_t)c * 128 + k] = __float2bfloat16(W[(size_t)k * 128 + c]);
        return;
    }
    if (bx < nbW + nbT) {
        int t = (bx - nbW) * 256 + tid;
        int tot = nrel * 4096;
        if (t >= 2 * tot) return;
        const float* src = (t < tot) ? att : msg;
        __hip_bfloat16* dst = (t < tot) ? Atab : Mtab;
        int u = (t < tot) ? t : t - tot;
        int rel = u >> 12, rem = u & 4095;
        int h = rem >> 10;  rem &= 1023;
        int s2 = rem >> 9;  rem &= 511;
        int lane = rem >> 3, j = rem & 7;
        int g = lane >> 4, c = lane & 15;
        dst[u] = __float2bfloat16(src[(size_t)rel * 4096 + h * 1024 + s2 * 16 + (g * 8 + j) * 32 + c]);
        return;
    }
    long i = ((long)(bx - nbW - nbT) * 256 + tid) * 4;
    if (i >= n4 * 4) return;
    float4 v = *(const float4*)(emb + i);
    u16x4 o;
    o[0] = f2b(v.x); o[1] = f2b(v.y); o[2] = f2b(v.z); o[3] = f2b(v.w);
    *(u16x4*)(embb + i) = o;
}

// ---------- fused count + QKV GEMM, 5:3 interleaved block roles ----------
// Count blocks stall on atomic round-trips; co-resident GEMM blocks fill
// the idle issue slots. Interleave keeps both types resident from dispatch 0.
__global__ __launch_bounds__(256) void qkv_count(
    const int* __restrict__ head, const int* __restrict__ etyp,
    const int* __restrict__ irow,
    unsigned* __restrict__ ecnt, unsigned* __restrict__ ucnt,
    unsigned* __restrict__ rcnt, int* __restrict__ plocalE,
    int* __restrict__ plocalU, int E, int NNZ, int nbX,
    const __hip_bfloat16* __restrict__ A,
    const __hip_bfloat16* __restrict__ WtQ, const __hip_bfloat16* __restrict__ WtK,
    const __hip_bfloat16* __restrict__ WtV,
    __hip_bfloat16* __restrict__ Qb, __hip_bfloat16* __restrict__ Kb,
    __hip_bfloat16* __restrict__ Vb, int n, int gg)
{
    __shared__ unsigned lcnt[NRELMAX];
    const int tid = threadIdx.x;
    const int bx = blockIdx.x;
    const int grp = bx >> 3, rem = bx & 7;
    if (rem < 5) {
        int ci = grp * 5 + rem;
        if (ci >= nbX) return;
        if (tid < NRELMAX) lcnt[tid] = 0;
        __syncthreads();
        int i = ci * 256 + tid;
        if (i < E) {
            unsigned p = atomicAdd(&ecnt[head[i]], 1u);
            plocalE[i] = (int)p;
            atomicAdd(&lcnt[etyp[i] - 1], 1u);
        }
        if (i < NNZ) {
            unsigned p = atomicAdd(&ucnt[irow[i]], 1u);
            plocalU[i] = (int)p;
        }
        __syncthreads();
        if (tid < NRELMAX) {
            unsigned c = lcnt[tid];
            if (c) atomicAdd(&rcnt[tid], c);
        }
        return;
    }
    int gi = grp * 3 + (rem - 5);
    if (gi >= 3 * gg) return;
    int which = gi / gg;
    int blk = gi % gg;
    const __hip_bfloat16* Wt = (which == 0) ? WtQ : (which == 1) ? WtK : WtV;
    __hip_bfloat16* Out = (which == 0) ? Qb : (which == 1) ? Kb : Vb;
    gemm_body<__hip_bfloat16>(A, Wt, Out, n, blk);
}

// ---------- hierarchical scans ----------
__global__ __launch_bounds__(1024) void scan_p1(
    unsigned* __restrict__ ecnt, int n_e, unsigned* __restrict__ bsumE,
    unsigned* __restrict__ ucnt, int n_u, unsigned* __restrict__ bsumU, int nbE)
{
    unsigned* buf; unsigned* bsum; int n; int blk;
    if ((int)blockIdx.x < nbE) { buf = ecnt; bsum = bsumE; n = n_e; blk = blockIdx.x; }
    else { buf = ucnt; bsum = bsumU; n = n_u; blk = blockIdx.x - nbE; }
    __shared__ unsigned sh[1024];
    int i = blk * 1024 + threadIdx.x;
    unsigned v = (i < n) ? buf[i] : 0u;
    sh[threadIdx.x] = v;
    __syncthreads();
    for (int off = 1; off < 1024; off <<= 1) {
        unsigned t = (threadIdx.x >= (unsigned)off) ? sh[threadIdx.x - off] : 0u;
        __syncthreads();
        sh[threadIdx.x] += t;
        __syncthreads();
    }
    if (i < n) buf[i] = sh[threadIdx.x] - v;  // exclusive
    if (threadIdx.x == 1023) bsum[blk] = sh[1023];
}

__global__ __launch_bounds__(1024) void scan_p2(
    unsigned* __restrict__ bsumE, int nbE, unsigned* __restrict__ bsumU, int nbU,
    const unsigned* __restrict__ rcnt, unsigned* __restrict__ rcur,
    unsigned* __restrict__ rend, unsigned* __restrict__ rnext, int nrel)
{
    if (blockIdx.x == 2) {
        if (threadIdx.x == 0) {
            unsigned acc = 0;
            for (int r = 0; r < nrel; ++r) {
                rcur[r] = acc;
                rend[r] = acc + rcnt[r];
                acc += (rcnt[r] + 15u) & ~15u;
                rnext[r] = acc;
            }
        }
        return;
    }
    unsigned* bsum = (blockIdx.x == 0) ? bsumE : bsumU;
    int nb = (blockIdx.x == 0) ? nbE : nbU;
    __shared__ unsigned sh[1024];
    unsigned v = (threadIdx.x < (unsigned)nb) ? bsum[threadIdx.x] : 0u;
    sh[threadIdx.x] = v;
    __syncthreads();
    for (int off = 1; off < 1024; off <<= 1) {
        unsigned t = (threadIdx.x >= (unsigned)off) ? sh[threadIdx.x - off] : 0u;
        __syncthreads();
        sh[threadIdx.x] += t;
        __syncthreads();
    }
    if (threadIdx.x < (unsigned)nb) bsum[threadIdx.x] = sh[threadIdx.x] - v;
}

__global__ __launch_bounds__(1024) void scan_p3(
    unsigned* __restrict__ ecnt, int n_e, const unsigned* __restrict__ bsumE,
    unsigned* __restrict__ ucnt, int n_u, const unsigned* __restrict__ bsumU, int nbE)
{
    unsigned* buf; const unsigned* bsum; int n; int blk;
    if ((int)blockIdx.x < nbE) { buf = ecnt; bsum = bsumE; n = n_e; blk = blockIdx.x; }
    else { buf = ucnt; bsum = bsumU; n = n_u; blk = blockIdx.x - nbE; }
    int i = blk * 1024 + threadIdx.x;
    if (i < n) buf[i] += bsum[blk];
}

// ---------- one-launch fills: user | edge | pads ----------
__global__ __launch_bounds__(256) void fills(
    const int* __restrict__ irow, const int* __restrict__ icol,
    const float* __restrict__ ival, const unsigned* __restrict__ ustart,
    const int* __restrict__ plocalU, int2* __restrict__ upair, int NNZ,
    const int* __restrict__ head, const int* __restrict__ tail,
    const int* __restrict__ etyp, const unsigned* __restrict__ estart,
    const int* __restrict__ plocalE, unsigned* __restrict__ rcur,
    int4* __restrict__ emeta, int E,
    const unsigned* __restrict__ rend, const unsigned* __restrict__ rnext,
    int nrel, long emax, int nbU, int nbE)
{
    __shared__ unsigned lcnt[NRELMAX];
    __shared__ unsigned lbase[NRELMAX];
    const int tid = threadIdx.x;
    const int bx = blockIdx.x;
    if (bx < nbU) {
        int i = bx * 256 + tid;
        if (i < NNZ) {
            unsigned slot = ustart[irow[i]] + (unsigned)plocalU[i];
            upair[slot] = make_int2(icol[i], __float_as_int(ival[i]));
        }
        return;
    }
    if (bx < nbU + nbE) {
        if (tid < NRELMAX) lcnt[tid] = 0;
        __syncthreads();
        int i = (bx - nbU) * 256 + tid;
        int r = 0;
        unsigned lpos = 0;
        if (i < E) {
            r = etyp[i] - 1;
            lpos = atomicAdd(&lcnt[r], 1u);
        }
        __syncthreads();
        if (tid < NRELMAX) {
            unsigned c = lcnt[tid];
            lbase[tid] = c ? atomicAdd(&rcur[tid], c) : 0u;
        }
        __syncthreads();
        if (i < E) {
            int hn = head[i];
            unsigned slot = estart[hn] + (unsigned)plocalE[i];
            emeta[lbase[r] + lpos] = make_int4(hn, tail[i], (int)slot, r);
        }
        return;
    }
    // pads (1 block)
    for (int r = 0; r < nrel; ++r) {
        unsigned s = rend[r], e2 = rnext[r];
        for (unsigned i = s + tid; i < e2; i += 256)
            emeta[i] = make_int4(0, 0, -1, r);
    }
    long ep = rnext[nrel - 1];
    for (long i = ep + tid; i < emax; i += 256)
        emeta[i] = make_int4(0, 0, -1, nrel - 1);
}

// ---------- fused edge pass (per head-pair ROUND): score + V' ----------
template <int ROUND>
__global__ __launch_bounds__(256, 4) void edge_pass(
    const __hip_bfloat16* __restrict__ Qb, const __hip_bfloat16* __restrict__ Kb,
    const __hip_bfloat16* __restrict__ Vb,
    const __hip_bfloat16* __restrict__ Atab, const __hip_bfloat16* __restrict__ Mtab,
    const int4* __restrict__ emeta, float* __restrict__ SC,
    __hip_bfloat16* __restrict__ VPh, long Epad, int chunk)
{
    const int wv = (blockIdx.x * 256 + threadIdx.x) >> 6;
    const int l = threadIdx.x & 63;
    const int g = l >> 4;
    const int c = l & 15;
    long j0 = (long)wv * chunk;
    if (j0 >= Epad) return;
    long j1 = j0 + chunk; if (j1 > Epad) j1 = Epad;

    bf16x8 aK[2][2], aM[2][2];
    int currel = -1;
    for (long pos = j0; pos < j1; pos += 16) {
        const int4 md = emeta[pos + c];
        const int rel0 = __shfl(md.w, 0, 64);   // rel-uniform group by construction
        if (rel0 != currel) {
            currel = rel0;
            #pragma unroll
            for (int hl = 0; hl < 2; ++hl) {
                const int h = ROUND * 2 + hl;
                #pragma unroll
                for (int s2 = 0; s2 < 2; ++s2) {
                    size_t idx = ((((size_t)rel0 * 4 + h) * 2 + s2) * 64 + l) * 8;
                    aK[hl][s2] = *(const bf16x8*)(Atab + idx);
                    aM[hl][s2] = *(const bf16x8*)(Mtab + idx);
                }
            }
        }
        const int tn = md.y, hn = md.x, slot = md.z;
        #pragma unroll
        for (int hl = 0; hl < 2; ++hl) {
            const int h = ROUND * 2 + hl;
            bf16x8 bk = *(const bf16x8*)(Kb + (size_t)tn * 128 + h * 32 + g * 8);
            bf16x8 bv = *(const bf16x8*)(Vb + (size_t)tn * 128 + h * 32 + g * 8);
            f32x4 z = {0.f, 0.f, 0.f, 0.f};
            f32x4 klo = __builtin_amdgcn_mfma_f32_16x16x32_bf16(aK[hl][0], bk, z, 0, 0, 0);
            f32x4 khi = __builtin_amdgcn_mfma_f32_16x16x32_bf16(aK[hl][1], bk, z, 0, 0, 0);
            f32x4 vlo = __builtin_amdgcn_mfma_f32_16x16x32_bf16(aM[hl][0], bv, z, 0, 0, 0);
            f32x4 vhi = __builtin_amdgcn_mfma_f32_16x16x32_bf16(aM[hl][1], bv, z, 0, 0, 0);
            const __hip_bfloat16* qp = Qb + (size_t)hn * 128 + h * 32;
            u16x4 q1 = *(const u16x4*)(qp + g * 4);
            u16x4 q2 = *(const u16x4*)(qp + 16 + g * 4);
            float p = 0.f;
            #pragma unroll
            for (int r = 0; r < 4; ++r)
                p += b2f(q1[r]) * klo[r] + b2f(q2[r]) * khi[r];
            p += __shfl_xor(p, 16, 64);
            p += __shfl_xor(p, 32, 64);
            if (slot >= 0) {
                if (g == 0) SC[(size_t)slot * 4 + h] = p * 0.17677669529663687f;
                u16x4 plo, phi;
                #pragma unroll
                for (int r = 0; r < 4; ++r) { plo[r] = f2b(vlo[r]); phi[r] = f2b(vhi[r]); }
                __hip_bfloat16* dst = VPh + (size_t)slot * 64 + hl * 32;
                *(u16x4*)(dst + g * 4) = plo;
                *(u16x4*)(dst + 16 + g * 4) = phi;
            }
        }
    }
}

// ---------- node pass (per head-pair ROUND): unroll-2 independent chains ----------
template <int ROUND>
__global__ __launch_bounds__(256) void node_pass(
    const float* __restrict__ SC, const __hip_bfloat16* __restrict__ VPh,
    const unsigned* __restrict__ estart, __hip_bfloat16* __restrict__ M, int n, int Etot)
{
    int node = (blockIdx.x * 256 + threadIdx.x) >> 6;
    if (node >= n) return;
    int l = threadIdx.x & 63;
    int half = l >> 5;
    const int h = ROUND * 2 + half;
    unsigned beg = estart[node];
    unsigned end = (node + 1 < n) ? estart[node + 1] : (unsigned)Etot;
    float mx = -INFINITY, dn = 0.f;
    unsigned j = beg;
    for (; j + 1 < end; j += 2) {
        float s0 = SC[(size_t)j * 4 + h];
        float s1 = SC[(size_t)(j + 1) * 4 + h];
        float m2 = fmaxf(mx, fmaxf(s0, s1));
        dn = dn * __expf(mx - m2) + __expf(s0 - m2) + __expf(s1 - m2);
        mx = m2;
    }
    if (j < end) {
        float s0 = SC[(size_t)j * 4 + h];
        float m2 = fmaxf(mx, s0);
        dn = dn * __expf(mx - m2) + __expf(s0 - m2);
        mx = m2;
    }
    float inv = (end > beg) ? 1.f / dn : 0.f;
    float acc0 = 0.f, acc1 = 0.f;
    j = beg;
    for (; j + 1 < end; j += 2) {
        float w0 = __expf(SC[(size_t)j * 4 + h] - mx) * inv;
        float w1 = __expf(SC[(size_t)(j + 1) * 4 + h] - mx) * inv;
        float e0 = __bfloat162float(VPh[(size_t)j * 64 + l]);
        float e1 = __bfloat162float(VPh[(size_t)(j + 1) * 64 + l]);
        acc0 = fmaf(w0, e0, acc0);
        acc1 = fmaf(w1, e1, acc1);
    }
    if (j < end) {
        float w0 = __expf(SC[(size_t)j * 4 + h] - mx) * inv;
        acc0 = fmaf(w0, __bfloat162float(VPh[(size_t)j * 64 + l]), acc0);
    }
    M[(size_t)node * 128 + ROUND * 64 + l] = __float2bfloat16(acc0 + acc1);
}

// ---------- per-user gather: 2 users/wave, unroll-8, 4 chains, bf16 emb ----------
__global__ __launch_bounds__(256) void user_gather(
    const __hip_bfloat16* __restrict__ embb, const unsigned* __restrict__ ustart,
    const int2* __restrict__ upair, float* __restrict__ out, int nu, int NNZ)
{
    int u = (blockIdx.x * 256 + threadIdx.x) >> 5;
    if (u >= nu) return;
    int l = threadIdx.x & 31;
    unsigned beg = ustart[u];
    unsigned end = (u + 1 < nu) ? ustart[u + 1] : (unsigned)NNZ;
    float a0 = 0.f, a1 = 0.f, a2 = 0.f, a3 = 0.f;
    float b0 = 0.f, b1 = 0.f, b2 = 0.f, b3 = 0.f;
    float c0 = 0.f, c1 = 0.f, c2 = 0.f, c3 = 0.f;
    float d0 = 0.f, d1 = 0.f, d2 = 0.f, d3 = 0.f;
    unsigned j = beg;
    for (; j + 7 < end; j += 8) {
        int2 p0 = upair[j], p1 = upair[j + 1], p2 = upair[j + 2], p3 = upair[j + 3];
        int2 p4 = upair[j + 4], p5 = upair[j + 5], p6 = upair[j + 6], p7 = upair[j + 7];
        uint2 e0 = *(const uint2*)((const unsigned*)(embb + (size_t)p0.x * 128) + l * 2);
        uint2 e1 = *(const uint2*)((const unsigned*)(embb + (size_t)p1.x * 128) + l * 2);
        uint2 e2 = *(const uint2*)((const unsigned*)(embb + (size_t)p2.x * 128) + l * 2);
        uint2 e3 = *(const uint2*)((const unsigned*)(embb + (size_t)p3.x * 128) + l * 2);
        uint2 e4 = *(const uint2*)((const unsigned*)(embb + (size_t)p4.x * 128) + l * 2);
        uint2 e5 = *(const uint2*)((const unsigned*)(embb + (size_t)p5.x * 128) + l * 2);
        uint2 e6 = *(const uint2*)((const unsigned*)(embb + (size_t)p6.x * 128) + l * 2);
        uint2 e7 = *(const uint2*)((const unsigned*)(embb + (size_t)p7.x * 128) + l * 2);
        float v0 = __int_as_float(p0.y), v1 = __int_as_float(p1.y);
        float v2 = __int_as_float(p2.y), v3 = __int_as_float(p3.y);
        float v4 = __int_as_float(p4.y), v5 = __int_as_float(p5.y);
        float v6 = __int_as_float(p6.y), v7 = __int_as_float(p7.y);
        a0 = fmaf(b2f((unsigned short)(e0.x & 0xFFFF)), v0, a0);
        a1 = fmaf(b2f((unsigned short)(e0.x >> 16)), v0, a1);
        a2 = fmaf(b2f((unsigned short)(e0.y & 0xFFFF)), v0, a2);
        a3 = fmaf(b2f((unsigned short)(e0.y >> 16)), v0, a3);
        b0 = fmaf(b2f((unsigned short)(e1.x & 0xFFFF)), v1, b0);
        b1 = fmaf(b2f((unsigned short)(e1.x >> 16)), v1, b1);
        b2 = fmaf(b2f((unsigned short)(e1.y & 0xFFFF)), v1, b2);
        b3 = fmaf(b2f((unsigned short)(e1.y >> 16)), v1, b3);
        c0 = fmaf(b2f((unsigned short)(e2.x & 0xFFFF)), v2, c0);
        c1 = fmaf(b2f((unsigned short)(e2.x >> 16)), v2, c1);
        c2 = fmaf(b2f((unsigned short)(e2.y & 0xFFFF)), v2, c2);
        c3 = fmaf(b2f((unsigned short)(e2.y >> 16)), v2, c3);
        d0 = fmaf(b2f((unsigned short)(e3.x & 0xFFFF)), v3, d0);
        d1 = fmaf(b2f((unsigned short)(e3.x >> 16)), v3, d1);
        d2 = fmaf(b2f((unsigned short)(e3.y & 0xFFFF)), v3, d2);
        d3 = fmaf(b2f((unsigned short)(e3.y >> 16)), v3, d3);
        a0 = fmaf(b2f((unsigned short)(e4.x & 0xFFFF)), v4, a0);
        a1 = fmaf(b2f((unsigned short)(e4.x >> 16)), v4, a1);
        a2 = fmaf(b2f((unsigned short)(e4.y & 0xFFFF)), v4, a2);
        a3 = fmaf(b2f((unsigned short)(e4.y >> 16)), v4, a3);
        b0 = fmaf(b2f((unsigned short)(e5.x & 0xFFFF)), v5, b0);
        b1 = fmaf(b2f((unsigned short)(e5.x >> 16)), v5, b1);
        b2 = fmaf(b2f((unsigned short)(e5.y & 0xFFFF)), v5, b2);
        b3 = fmaf(b2f((unsigned short)(e5.y >> 16)), v5, b3);
        c0 = fmaf(b2f((unsigned short)(e6.x & 0xFFFF)), v6, c0);
        c1 = fmaf(b2f((unsigned short)(e6.x >> 16)), v6, c1);
        c2 = fmaf(b2f((unsigned short)(e6.y & 0xFFFF)), v6, c2);
        c3 = fmaf(b2f((unsigned short)(e6.y >> 16)), v6, c3);
        d0 = fmaf(b2f((unsigned short)(e7.x & 0xFFFF)), v7, d0);
        d1 = fmaf(b2f((unsigned short)(e7.x >> 16)), v7, d1);
        d2 = fmaf(b2f((unsigned short)(e7.y & 0xFFFF)), v7, d2);
        d3 = fmaf(b2f((unsigned short)(e7.y >> 16)), v7, d3);
    }
    for (; j < end; ++j) {
        int2 p0 = upair[j];
        float v0 = __int_as_float(p0.y);
        uint2 e0 = *(const uint2*)((const unsigned*)(embb + (size_t)p0.x * 128) + l * 2);
        a0 = fmaf(b2f((unsigned short)(e0.x & 0xFFFF)), v0, a0);
        a1 = fmaf(b2f((unsigned short)(e0.x >> 16)), v0, a1);
        a2 = fmaf(b2f((unsigned short)(e0.y & 0xFFFF)), v0, a2);
        a3 = fmaf(b2f((unsigned short)(e0.y >> 16)), v0, a3);
    }
    *(float4*)(out + (size_t)u * 128 + l * 4) =
        make_float4(a0 + b0 + c0 + d0, a1 + b1 + c1 + d1,
                    a2 + b2 + c2 + d2, a3 + b3 + c3 + d3);
}

extern "C" void kernel_launch(void* const* d_in, const int* in_sizes, int n_in,
                              void* d_out, int out_size, void* d_ws, size_t ws_size,
                              hipStream_t stream)
{
    const float* emb = (const float*)d_in[0];
    const float* W_Q = (const float*)d_in[1];
    const float* W_K = (const float*)d_in[2];
    const float* W_V = (const float*)d_in[3];
    const float* W_O = (const float*)d_in[4];
    const float* att = (const float*)d_in[5];
    const float* msg = (const float*)d_in[6];
    const int* eidx  = (const int*)d_in[8];
    const int* etyp  = (const int*)d_in[9];
    const int* irow  = (const int*)d_in[10];
    const int* icol  = (const int*)d_in[11];
    const float* ival = (const float*)d_in[12];

    const int N    = in_sizes[0] / 128;
    const int E    = in_sizes[8] / 2;
    const int NNZ  = in_sizes[10];
    const int NU   = out_size / 128 - N;
    const int NREL = in_sizes[5] / 4096;

    const int* head = eidx;
    const int* tail = eidx + E;

    const int NUp = (NU + 255) & ~255;

    // ---- d_ws layout (~154 MB; proven capacity >= 163 MB) ----
    const size_t NC = (size_t)N * 128;
    char* p = (char*)d_ws;
    __hip_bfloat16* VPh = (__hip_bfloat16*)p; p += (size_t)E * 64 * 2;  // 76.8 MB
    __hip_bfloat16* Kb  = (__hip_bfloat16*)p; p += NC * 2;              // 25.6 MB
    __hip_bfloat16* Vb  = (__hip_bfloat16*)p; p += NC * 2;              // 25.6 MB
    __hip_bfloat16* M   = (__hip_bfloat16*)p; p += NC * 2;              // 25.6 MB
    unsigned* rcnt  = (unsigned*)p; p += 32 * 4;
    unsigned* rcur  = (unsigned*)p; p += 32 * 4;
    unsigned* rend  = (unsigned*)p; p += 32 * 4;
    unsigned* rnext = (unsigned*)p; p += 32 * 4;
    unsigned* ucnt  = (unsigned*)p; p += (size_t)NUp * 4;   // counts -> starts
    unsigned* bsumE = (unsigned*)p; p += 1024 * 4;
    unsigned* bsumU = (unsigned*)p; p += 1024 * 4;
    int2* upair     = (int2*)p;     p += (size_t)NNZ * 8;   // (col, val) pairs
    __hip_bfloat16* WtQ = (__hip_bfloat16*)p; p += 16384 * 2;
    __hip_bfloat16* WtK = (__hip_bfloat16*)p; p += 16384 * 2;
    __hip_bfloat16* WtV = (__hip_bfloat16*)p; p += 16384 * 2;
    __hip_bfloat16* WtO = (__hip_bfloat16*)p; p += 16384 * 2;
    __hip_bfloat16* Atab = (__hip_bfloat16*)p; p += (size_t)NREL * 4096 * 2;
    __hip_bfloat16* Mtab = (__hip_bfloat16*)p; p += (size_t)NREL * 4096 * 2;

    // CSR-phase overlay inside VPh (dead until edge_pass):
    int* plocalU = (int*)VPh;            // NNZ ints
    int* plocalE = plocalU + NNZ;        // E ints

    // ---- d_out overlays (all regions fully rewritten by final kernels) ----
    float* out_ent = (float*)d_out;
    float* out_usr = out_ent + NC;
    __hip_bfloat16* embb = (__hip_bfloat16*)out_ent;                 // 25.6 MB
    __hip_bfloat16* Qb   = (__hip_bfloat16*)((char*)d_out + NC * 2); // 25.6 MB
    const long Emax = E + 512;
    float* SC   = out_usr;                                            // E*4 f32
    int4* emeta = (int4*)(out_usr + (size_t)E * 4);                   // Emax int4
    unsigned* ecnt = (unsigned*)((char*)emeta + (size_t)Emax * 16);   // N u32 (counts -> starts)

    hipMemsetAsync(rcnt, 0, (size_t)(4 * 32 * 4) + (size_t)NUp * 4, stream);  // rcnt..ucnt
    hipMemsetAsync(ecnt, 0, (size_t)N * 4, stream);

    // prep: weights, tables, emb-bf16 (streaming)
    const int nbW = 256;                               // 65536 / 256
    const int nbT = (2 * NREL * 4096 + 255) / 256;
    const int nbC = (int)((NC / 4 + 255) / 256);
    prep<<<nbW + nbT + nbC, 256, 0, stream>>>(
        W_Q, W_K, W_V, W_O, WtQ, WtK, WtV, WtO,
        att, msg, Atab, Mtab, NREL,
        emb, embb, (long)(NC / 4), nbW, nbT);

    // fused count + QKV GEMM, 5:3 interleaved for co-residency
    int gg = (N + 127) / 128;
    const int nbX = ((NNZ > E ? NNZ : E) + 255) / 256;
    int grpC = (nbX + 4) / 5;
    int grpG = (3 * gg + 2) / 3;
    int ngrp = (grpC > grpG) ? grpC : grpG;
    qkv_count<<<ngrp * 8, 256, 0, stream>>>(
        head, etyp, irow, ecnt, ucnt, rcnt, plocalE, plocalU, E, NNZ, nbX,
        embb, WtQ, WtK, WtV, Qb, Kb, Vb, N, gg);

    // hierarchical scans (wide, 3 launches)
    int nbE2 = (N + 1023) / 1024;
    int nbU2 = (NU + 1023) / 1024;
    scan_p1<<<nbE2 + nbU2, 1024, 0, stream>>>(ecnt, N, bsumE, ucnt, NU, bsumU, nbE2);
    scan_p2<<<3, 1024, 0, stream>>>(bsumE, nbE2, bsumU, nbU2, rcnt, rcur, rend, rnext, NREL);
    scan_p3<<<nbE2 + nbU2, 1024, 0, stream>>>(ecnt, N, bsumE, ucnt, NU, bsumU, nbE2);

    // fills (user pairs, rel-sorted emeta, pads) in one launch
    const int nbU = (NNZ + 255) / 256;
    const int nbE = (E + 255) / 256;
    fills<<<nbU + nbE + 1, 256, 0, stream>>>(
        irow, icol, ival, ucnt, plocalU, upair, NNZ,
        head, tail, etyp, ecnt, plocalE, rcur, emeta, E,
        rend, rnext, NREL, Emax, nbU, nbE);

    // edge + node passes (per head-pair)
    const int NWAVE = 16384;
    int chunk = (int)(((Emax + NWAVE - 1) / NWAVE + 15) & ~15L);
    edge_pass<0><<<NWAVE / 4, 256, 0, stream>>>(Qb, Kb, Vb, Atab, Mtab, emeta, SC, VPh, Emax, chunk);
    node_pass<0><<<(N + 3) / 4, 256, 0, stream>>>(SC, VPh, ecnt, M, N, E);
    edge_pass<1><<<NWAVE / 4, 256, 0, stream>>>(Qb, Kb, Vb, Atab, Mtab, emeta, SC, VPh, Emax, chunk);
    node_pass<1><<<(N + 3) / 4, 256, 0, stream>>>(SC, VPh, ecnt, M, N, E);

    // user aggregation (reads embb + upair; overwrites SC/emeta/ecnt = dead)
    user_gather<<<(NU + 7) / 8, 256, 0, stream>>>(embb, ucnt, upair, out_usr, NU, NNZ);

    // entity output GEMM last (overwrites embb+Qb region = dead)
    mfma_gemm<float><<<gg, 256, 0, stream>>>(M, WtO, out_ent, N);
}

// Round 23
// 528.045 us; speedup vs baseline: 1.0312x; 1.0312x over previous
//
#include <hip/hip_runtime.h>
#include <hip/hip_bf16.h>
#include <math.h>

typedef __attribute__((ext_vector_type(8))) unsigned short u16x8;
typedef __attribute__((ext_vector_type(4))) unsigned short u16x4;
typedef __attribute__((ext_vector_type(8))) short bf16x8;   // MFMA A/B frag (8 bf16)
typedef __attribute__((ext_vector_type(4))) float f32x4;    // MFMA C/D frag

#define NRELMAX 32

__device__ __forceinline__ float b2f(unsigned short u) {
    return __uint_as_float(((unsigned)u) << 16);
}
__device__ __forceinline__ unsigned short f2b(float v) {
    __hip_bfloat16 b = __float2bfloat16(v);
    return *reinterpret_cast<unsigned short*>(&b);
}

// ---------- MFMA GEMM (m89-verified wiring) ----------
__device__ __forceinline__ bf16x8 lda_frag(const __hip_bfloat16* p) {
    return *(const bf16x8*)p;
}
__device__ __forceinline__ void st_o(__hip_bfloat16* p, float v) { *p = __float2bfloat16(v); }
__device__ __forceinline__ void st_o(float* p, float v) { *p = v; }

template <typename TO>
__device__ __forceinline__ void gemm_body(const __hip_bfloat16* __restrict__ A,
                                          const __hip_bfloat16* __restrict__ Wt,
                                          TO* __restrict__ out, int n, int blk)
{
    const int tid = threadIdx.x;
    const int w = tid >> 6;
    const int l = tid & 63;
    const int q = l >> 4;
    const int c16 = l & 15;
    const int wr = (w >> 1) * 64;
    const int wc = (w & 1) * 64;
    const long row0 = (long)blk * 128;

    f32x4 acc[4][4] = {};
    #pragma unroll
    for (int ks = 0; ks < 4; ++ks) {
        bf16x8 af[4];
        #pragma unroll
        for (int rb = 0; rb < 4; ++rb) {
            long r = row0 + wr + rb * 16 + c16;
            if (r >= n) r = n - 1;
            af[rb] = lda_frag(A + r * 128 + ks * 32 + q * 8);
        }
        #pragma unroll
        for (int cb = 0; cb < 4; ++cb) {
            bf16x8 wf = *(const bf16x8*)(Wt + (size_t)(wc + cb * 16 + c16) * 128 + ks * 32 + q * 8);
            #pragma unroll
            for (int rb = 0; rb < 4; ++rb)
                acc[rb][cb] = __builtin_amdgcn_mfma_f32_16x16x32_bf16(af[rb], wf, acc[rb][cb], 0, 0, 0);
        }
    }
    #pragma unroll
    for (int rb = 0; rb < 4; ++rb) {
        #pragma unroll
        for (int r = 0; r < 4; ++r) {
            long row = row0 + wr + rb * 16 + q * 4 + r;
            if (row < n) {
                #pragma unroll
                for (int cb = 0; cb < 4; ++cb)
                    st_o(out + row * 128 + wc + cb * 16 + c16, acc[rb][cb][r]);
            }
        }
    }
}

template <typename TO>
__global__ __launch_bounds__(256) void mfma_gemm(const __hip_bfloat16* __restrict__ A,
                                                 const __hip_bfloat16* __restrict__ Wt,
                                                 TO* __restrict__ out, int n)
{
    gemm_body<TO>(A, Wt, out, n, blockIdx.x);
}

// ---------- prep: trans_w | conv_tab | conv_emb (streaming) ----------
__global__ __launch_bounds__(256) void prep(
    const float* __restrict__ W0, const float* __restrict__ W1,
    const float* __restrict__ W2, const float* __restrict__ W3,
    __hip_bfloat16* __restrict__ T0, __hip_bfloat16* __restrict__ T1,
    __hip_bfloat16* __restrict__ T2, __hip_bfloat16* __restrict__ T3,
    const float* __restrict__ att, const float* __restrict__ msg,
    __hip_bfloat16* __restrict__ Atab, __hip_bfloat16* __restrict__ Mtab, int nrel,
    const float* __restrict__ emb, __hip_bfloat16* __restrict__ embb, long n4,
    int nbW, int nbT)
{
    const int tid = threadIdx.x;
    const int bx = blockIdx.x;
    if (bx < nbW) {
        int t = bx * 256 + tid;
        int w = t >> 14, r = t & 16383;
        const float* W = (w == 0) ? W0 : (w == 1) ? W1 : (w == 2) ? W2 : W3;
        __hip_bfloat16* T = (w == 0) ? T0 : (w == 1) ? T1 : (w == 2) ? T2 : T3;
        int k = r >> 7, c = r & 127;
        T[(size_t)c * 128 + k] = __float2bfloat16(W[(size_t)k * 128 + c]);
        return;
    }
    if (bx < nbW + nbT) {
        int t = (bx - nbW) * 256 + tid;
        int tot = nrel * 4096;
        if (t >= 2 * tot) return;
        const float* src = (t < tot) ? att : msg;
        __hip_bfloat16* dst = (t < tot) ? Atab : Mtab;
        int u = (t < tot) ? t : t - tot;
        int rel = u >> 12, rem = u & 4095;
        int h = rem >> 10;  rem &= 1023;
        int s2 = rem >> 9;  rem &= 511;
        int lane = rem >> 3, j = rem & 7;
        int g = lane >> 4, c = lane & 15;
        dst[u] = __float2bfloat16(src[(size_t)rel * 4096 + h * 1024 + s2 * 16 + (g * 8 + j) * 32 + c]);
        return;
    }
    long i = ((long)(bx - nbW - nbT) * 256 + tid) * 4;
    if (i >= n4 * 4) return;
    float4 v = *(const float4*)(emb + i);
    u16x4 o;
    o[0] = f2b(v.x); o[1] = f2b(v.y); o[2] = f2b(v.z); o[3] = f2b(v.w);
    *(u16x4*)(embb + i) = o;
}

// ---------- fused count + QKV GEMM ----------
__global__ __launch_bounds__(256) void qkv_count(
    const int* __restrict__ head, const int* __restrict__ etyp,
    const int* __restrict__ irow,
    unsigned* __restrict__ ecnt, unsigned* __restrict__ ucnt,
    unsigned* __restrict__ rcnt, int* __restrict__ plocalE,
    int* __restrict__ plocalU, int E, int NNZ, int nbX,
    const __hip_bfloat16* __restrict__ A,
    const __hip_bfloat16* __restrict__ WtQ, const __hip_bfloat16* __restrict__ WtK,
    const __hip_bfloat16* __restrict__ WtV,
    __hip_bfloat16* __restrict__ Qb, __hip_bfloat16* __restrict__ Kb,
    __hip_bfloat16* __restrict__ Vb, int n, int gg)
{
    __shared__ unsigned lcnt[NRELMAX];
    const int tid = threadIdx.x;
    const int bx = blockIdx.x;
    if (bx < nbX) {
        if (tid < NRELMAX) lcnt[tid] = 0;
        __syncthreads();
        int i = bx * 256 + tid;
        if (i < E) {
            unsigned p = atomicAdd(&ecnt[head[i]], 1u);
            plocalE[i] = (int)p;
            atomicAdd(&lcnt[etyp[i] - 1], 1u);
        }
        if (i < NNZ) {
            unsigned p = atomicAdd(&ucnt[irow[i]], 1u);
            plocalU[i] = (int)p;
        }
        __syncthreads();
        if (tid < NRELMAX) {
            unsigned c = lcnt[tid];
            if (c) atomicAdd(&rcnt[tid], c);
        }
        return;
    }
    int b2 = bx - nbX;
    int which = b2 / gg;
    int blk = b2 % gg;
    const __hip_bfloat16* Wt = (which == 0) ? WtQ : (which == 1) ? WtK : WtV;
    __hip_bfloat16* Out = (which == 0) ? Qb : (which == 1) ? Kb : Vb;
    gemm_body<__hip_bfloat16>(A, Wt, Out, n, blk);
}

// ---------- hierarchical scans ----------
__global__ __launch_bounds__(1024) void scan_p1(
    unsigned* __restrict__ ecnt, int n_e, unsigned* __restrict__ bsumE,
    unsigned* __restrict__ ucnt, int n_u, unsigned* __restrict__ bsumU, int nbE)
{
    unsigned* buf; unsigned* bsum; int n; int blk;
    if ((int)blockIdx.x < nbE) { buf = ecnt; bsum = bsumE; n = n_e; blk = blockIdx.x; }
    else { buf = ucnt; bsum = bsumU; n = n_u; blk = blockIdx.x - nbE; }
    __shared__ unsigned sh[1024];
    int i = blk * 1024 + threadIdx.x;
    unsigned v = (i < n) ? buf[i] : 0u;
    sh[threadIdx.x] = v;
    __syncthreads();
    for (int off = 1; off < 1024; off <<= 1) {
        unsigned t = (threadIdx.x >= (unsigned)off) ? sh[threadIdx.x - off] : 0u;
        __syncthreads();
        sh[threadIdx.x] += t;
        __syncthreads();
    }
    if (i < n) buf[i] = sh[threadIdx.x] - v;  // exclusive
    if (threadIdx.x == 1023) bsum[blk] = sh[1023];
}

__global__ __launch_bounds__(1024) void scan_p2(
    unsigned* __restrict__ bsumE, int nbE, unsigned* __restrict__ bsumU, int nbU,
    const unsigned* __restrict__ rcnt, unsigned* __restrict__ rcur,
    unsigned* __restrict__ rend, unsigned* __restrict__ rnext, int nrel)
{
    if (blockIdx.x == 2) {
        if (threadIdx.x == 0) {
            unsigned acc = 0;
            for (int r = 0; r < nrel; ++r) {
                rcur[r] = acc;
                rend[r] = acc + rcnt[r];
                acc += (rcnt[r] + 15u) & ~15u;
                rnext[r] = acc;
            }
        }
        return;
    }
    unsigned* bsum = (blockIdx.x == 0) ? bsumE : bsumU;
    int nb = (blockIdx.x == 0) ? nbE : nbU;
    __shared__ unsigned sh[1024];
    unsigned v = (threadIdx.x < (unsigned)nb) ? bsum[threadIdx.x] : 0u;
    sh[threadIdx.x] = v;
    __syncthreads();
    for (int off = 1; off < 1024; off <<= 1) {
        unsigned t = (threadIdx.x >= (unsigned)off) ? sh[threadIdx.x - off] : 0u;
        __syncthreads();
        sh[threadIdx.x] += t;
        __syncthreads();
    }
    if (threadIdx.x < (unsigned)nb) bsum[threadIdx.x] = sh[threadIdx.x] - v;
}

__global__ __launch_bounds__(1024) void scan_p3(
    unsigned* __restrict__ ecnt, int n_e, const unsigned* __restrict__ bsumE,
    unsigned* __restrict__ ucnt, int n_u, const unsigned* __restrict__ bsumU, int nbE)
{
    unsigned* buf; const unsigned* bsum; int n; int blk;
    if ((int)blockIdx.x < nbE) { buf = ecnt; bsum = bsumE; n = n_e; blk = blockIdx.x; }
    else { buf = ucnt; bsum = bsumU; n = n_u; blk = blockIdx.x - nbE; }
    int i = blk * 1024 + threadIdx.x;
    if (i < n) buf[i] += bsum[blk];
}

// ---------- one-launch fills: user | edge | pads ----------
__global__ __launch_bounds__(256) void fills(
    const int* __restrict__ irow, const int* __restrict__ icol,
    const float* __restrict__ ival, const unsigned* __restrict__ ustart,
    const int* __restrict__ plocalU, int2* __restrict__ upair, int NNZ,
    const int* __restrict__ head, const int* __restrict__ tail,
    const int* __restrict__ etyp, const unsigned* __restrict__ estart,
    const int* __restrict__ plocalE, unsigned* __restrict__ rcur,
    int4* __restrict__ emeta, int E,
    const unsigned* __restrict__ rend, const unsigned* __restrict__ rnext,
    int nrel, long emax, int nbU, int nbE)
{
    __shared__ unsigned lcnt[NRELMAX];
    __shared__ unsigned lbase[NRELMAX];
    const int tid = threadIdx.x;
    const int bx = blockIdx.x;
    if (bx < nbU) {
        int i = bx * 256 + tid;
        if (i < NNZ) {
            unsigned slot = ustart[irow[i]] + (unsigned)plocalU[i];
            upair[slot] = make_int2(icol[i], __float_as_int(ival[i]));
        }
        return;
    }
    if (bx < nbU + nbE) {
        if (tid < NRELMAX) lcnt[tid] = 0;
        __syncthreads();
        int i = (bx - nbU) * 256 + tid;
        int r = 0;
        unsigned lpos = 0;
        if (i < E) {
            r = etyp[i] - 1;
            lpos = atomicAdd(&lcnt[r], 1u);
        }
        __syncthreads();
        if (tid < NRELMAX) {
            unsigned c = lcnt[tid];
            lbase[tid] = c ? atomicAdd(&rcur[tid], c) : 0u;
        }
        __syncthreads();
        if (i < E) {
            int hn = head[i];
            unsigned slot = estart[hn] + (unsigned)plocalE[i];
            emeta[lbase[r] + lpos] = make_int4(hn, tail[i], (int)slot, r);
        }
        return;
    }
    // pads (1 block)
    for (int r = 0; r < nrel; ++r) {
        unsigned s = rend[r], e2 = rnext[r];
        for (unsigned i = s + tid; i < e2; i += 256)
            emeta[i] = make_int4(0, 0, -1, r);
    }
    long ep = rnext[nrel - 1];
    for (long i = ep + tid; i < emax; i += 256)
        emeta[i] = make_int4(0, 0, -1, nrel - 1);
}

// ---------- fused edge pass (per head-pair ROUND): score + V' ----------
template <int ROUND>
__global__ __launch_bounds__(256, 4) void edge_pass(
    const __hip_bfloat16* __restrict__ Qb, const __hip_bfloat16* __restrict__ Kb,
    const __hip_bfloat16* __restrict__ Vb,
    const __hip_bfloat16* __restrict__ Atab, const __hip_bfloat16* __restrict__ Mtab,
    const int4* __restrict__ emeta, float* __restrict__ SC,
    __hip_bfloat16* __restrict__ VPh, long Epad, int chunk)
{
    const int wv = (blockIdx.x * 256 + threadIdx.x) >> 6;
    const int l = threadIdx.x & 63;
    const int g = l >> 4;
    const int c = l & 15;
    long j0 = (long)wv * chunk;
    if (j0 >= Epad) return;
    long j1 = j0 + chunk; if (j1 > Epad) j1 = Epad;

    bf16x8 aK[2][2], aM[2][2];
    int currel = -1;
    for (long pos = j0; pos < j1; pos += 16) {
        const int4 md = emeta[pos + c];
        const int rel0 = __shfl(md.w, 0, 64);   // rel-uniform group by construction
        if (rel0 != currel) {
            currel = rel0;
            #pragma unroll
            for (int hl = 0; hl < 2; ++hl) {
                const int h = ROUND * 2 + hl;
                #pragma unroll
                for (int s2 = 0; s2 < 2; ++s2) {
                    size_t idx = ((((size_t)rel0 * 4 + h) * 2 + s2) * 64 + l) * 8;
                    aK[hl][s2] = *(const bf16x8*)(Atab + idx);
                    aM[hl][s2] = *(const bf16x8*)(Mtab + idx);
                }
            }
        }
        const int tn = md.y, hn = md.x, slot = md.z;
        #pragma unroll
        for (int hl = 0; hl < 2; ++hl) {
            const int h = ROUND * 2 + hl;
            bf16x8 bk = *(const bf16x8*)(Kb + (size_t)tn * 128 + h * 32 + g * 8);
            bf16x8 bv = *(const bf16x8*)(Vb + (size_t)tn * 128 + h * 32 + g * 8);
            f32x4 z = {0.f, 0.f, 0.f, 0.f};
            f32x4 klo = __builtin_amdgcn_mfma_f32_16x16x32_bf16(aK[hl][0], bk, z, 0, 0, 0);
            f32x4 khi = __builtin_amdgcn_mfma_f32_16x16x32_bf16(aK[hl][1], bk, z, 0, 0, 0);
            f32x4 vlo = __builtin_amdgcn_mfma_f32_16x16x32_bf16(aM[hl][0], bv, z, 0, 0, 0);
            f32x4 vhi = __builtin_amdgcn_mfma_f32_16x16x32_bf16(aM[hl][1], bv, z, 0, 0, 0);
            const __hip_bfloat16* qp = Qb + (size_t)hn * 128 + h * 32;
            u16x4 q1 = *(const u16x4*)(qp + g * 4);
            u16x4 q2 = *(const u16x4*)(qp + 16 + g * 4);
            float p = 0.f;
            #pragma unroll
            for (int r = 0; r < 4; ++r)
                p += b2f(q1[r]) * klo[r] + b2f(q2[r]) * khi[r];
            p += __shfl_xor(p, 16, 64);
            p += __shfl_xor(p, 32, 64);
            if (slot >= 0) {
                if (g == 0) SC[(size_t)slot * 4 + h] = p * 0.17677669529663687f;
                u16x4 plo, phi;
                #pragma unroll
                for (int r = 0; r < 4; ++r) { plo[r] = f2b(vlo[r]); phi[r] = f2b(vhi[r]); }
                __hip_bfloat16* dst = VPh + (size_t)slot * 64 + hl * 32;
                *(u16x4*)(dst + g * 4) = plo;
                *(u16x4*)(dst + 16 + g * 4) = phi;
            }
        }
    }
}

// ---------- node pass (per head-pair ROUND): unroll-2 independent chains ----------
template <int ROUND>
__global__ __launch_bounds__(256) void node_pass(
    const float* __restrict__ SC, const __hip_bfloat16* __restrict__ VPh,
    const unsigned* __restrict__ estart, __hip_bfloat16* __restrict__ M, int n, int Etot)
{
    int node = (blockIdx.x * 256 + threadIdx.x) >> 6;
    if (node >= n) return;
    int l = threadIdx.x & 63;
    int half = l >> 5;
    const int h = ROUND * 2 + half;
    unsigned beg = estart[node];
    unsigned end = (node + 1 < n) ? estart[node + 1] : (unsigned)Etot;
    float mx = -INFINITY, dn = 0.f;
    unsigned j = beg;
    for (; j + 1 < end; j += 2) {
        float s0 = SC[(size_t)j * 4 + h];
        float s1 = SC[(size_t)(j + 1) * 4 + h];
        float m2 = fmaxf(mx, fmaxf(s0, s1));
        dn = dn * __expf(mx - m2) + __expf(s0 - m2) + __expf(s1 - m2);
        mx = m2;
    }
    if (j < end) {
        float s0 = SC[(size_t)j * 4 + h];
        float m2 = fmaxf(mx, s0);
        dn = dn * __expf(mx - m2) + __expf(s0 - m2);
        mx = m2;
    }
    float inv = (end > beg) ? 1.f / dn : 0.f;
    float acc0 = 0.f, acc1 = 0.f;
    j = beg;
    for (; j + 1 < end; j += 2) {
        float w0 = __expf(SC[(size_t)j * 4 + h] - mx) * inv;
        float w1 = __expf(SC[(size_t)(j + 1) * 4 + h] - mx) * inv;
        float e0 = __bfloat162float(VPh[(size_t)j * 64 + l]);
        float e1 = __bfloat162float(VPh[(size_t)(j + 1) * 64 + l]);
        acc0 = fmaf(w0, e0, acc0);
        acc1 = fmaf(w1, e1, acc1);
    }
    if (j < end) {
        float w0 = __expf(SC[(size_t)j * 4 + h] - mx) * inv;
        acc0 = fmaf(w0, __bfloat162float(VPh[(size_t)j * 64 + l]), acc0);
    }
    M[(size_t)node * 128 + ROUND * 64 + l] = __float2bfloat16(acc0 + acc1);
}

// ---------- per-user gather: 2 users/wave, unroll-4, int2 pairs, bf16 emb ----------
__global__ __launch_bounds__(256) void user_gather(
    const __hip_bfloat16* __restrict__ embb, const unsigned* __restrict__ ustart,
    const int2* __restrict__ upair, float* __restrict__ out, int nu, int NNZ)
{
    int u = (blockIdx.x * 256 + threadIdx.x) >> 5;
    if (u >= nu) return;
    int l = threadIdx.x & 31;
    unsigned beg = ustart[u];
    unsigned end = (u + 1 < nu) ? ustart[u + 1] : (unsigned)NNZ;
    float a0 = 0.f, a1 = 0.f, a2 = 0.f, a3 = 0.f;
    float b0 = 0.f, b1 = 0.f, b2 = 0.f, b3 = 0.f;
    unsigned j = beg;
    for (; j + 3 < end; j += 4) {
        int2 p0 = upair[j], p1 = upair[j + 1], p2 = upair[j + 2], p3 = upair[j + 3];
        float v0 = __int_as_float(p0.y), v1 = __int_as_float(p1.y);
        float v2 = __int_as_float(p2.y), v3 = __int_as_float(p3.y);
        uint2 e0 = *(const uint2*)((const unsigned*)(embb + (size_t)p0.x * 128) + l * 2);
        uint2 e1 = *(const uint2*)((const unsigned*)(embb + (size_t)p1.x * 128) + l * 2);
        uint2 e2 = *(const uint2*)((const unsigned*)(embb + (size_t)p2.x * 128) + l * 2);
        uint2 e3 = *(const uint2*)((const unsigned*)(embb + (size_t)p3.x * 128) + l * 2);
        a0 = fmaf(b2f((unsigned short)(e0.x & 0xFFFF)), v0, a0);
        a1 = fmaf(b2f((unsigned short)(e0.x >> 16)), v0, a1);
        a2 = fmaf(b2f((unsigned short)(e0.y & 0xFFFF)), v0, a2);
        a3 = fmaf(b2f((unsigned short)(e0.y >> 16)), v0, a3);
        b0 = fmaf(b2f((unsigned short)(e1.x & 0xFFFF)), v1, b0);
        b1 = fmaf(b2f((unsigned short)(e1.x >> 16)), v1, b1);
        b2 = fmaf(b2f((unsigned short)(e1.y & 0xFFFF)), v1, b2);
        b3 = fmaf(b2f((unsigned short)(e1.y >> 16)), v1, b3);
        a0 = fmaf(b2f((unsigned short)(e2.x & 0xFFFF)), v2, a0);
        a1 = fmaf(b2f((unsigned short)(e2.x >> 16)), v2, a1);
        a2 = fmaf(b2f((unsigned short)(e2.y & 0xFFFF)), v2, a2);
        a3 = fmaf(b2f((unsigned short)(e2.y >> 16)), v2, a3);
        b0 = fmaf(b2f((unsigned short)(e3.x & 0xFFFF)), v3, b0);
        b1 = fmaf(b2f((unsigned short)(e3.x >> 16)), v3, b1);
        b2 = fmaf(b2f((unsigned short)(e3.y & 0xFFFF)), v3, b2);
        b3 = fmaf(b2f((unsigned short)(e3.y >> 16)), v3, b3);
    }
    for (; j < end; ++j) {
        int2 p0 = upair[j];
        float v0 = __int_as_float(p0.y);
        uint2 e0 = *(const uint2*)((const unsigned*)(embb + (size_t)p0.x * 128) + l * 2);
        a0 = fmaf(b2f((unsigned short)(e0.x & 0xFFFF)), v0, a0);
        a1 = fmaf(b2f((unsigned short)(e0.x >> 16)), v0, a1);
        a2 = fmaf(b2f((unsigned short)(e0.y & 0xFFFF)), v0, a2);
        a3 = fmaf(b2f((unsigned short)(e0.y >> 16)), v0, a3);
    }
    *(float4*)(out + (size_t)u * 128 + l * 4) =
        make_float4(a0 + b0, a1 + b1, a2 + b2, a3 + b3);
}

extern "C" void kernel_launch(void* const* d_in, const int* in_sizes, int n_in,
                              void* d_out, int out_size, void* d_ws, size_t ws_size,
                              hipStream_t stream)
{
    const float* emb = (const float*)d_in[0];
    const float* W_Q = (const float*)d_in[1];
    const float* W_K = (const float*)d_in[2];
    const float* W_V = (const float*)d_in[3];
    const float* W_O = (const float*)d_in[4];
    const float* att = (const float*)d_in[5];
    const float* msg = (const float*)d_in[6];
    const int* eidx  = (const int*)d_in[8];
    const int* etyp  = (const int*)d_in[9];
    const int* irow  = (const int*)d_in[10];
    const int* icol  = (const int*)d_in[11];
    const float* ival = (const float*)d_in[12];

    const int N    = in_sizes[0] / 128;
    const int E    = in_sizes[8] / 2;
    const int NNZ  = in_sizes[10];
    const int NU   = out_size / 128 - N;
    const int NREL = in_sizes[5] / 4096;

    const int* head = eidx;
    const int* tail = eidx + E;

    const int NUp = (NU + 255) & ~255;

    // ---- d_ws layout (~154 MB; proven capacity >= 163 MB) ----
    const size_t NC = (size_t)N * 128;
    char* p = (char*)d_ws;
    __hip_bfloat16* VPh = (__hip_bfloat16*)p; p += (size_t)E * 64 * 2;  // 76.8 MB
    __hip_bfloat16* Kb  = (__hip_bfloat16*)p; p += NC * 2;              // 25.6 MB
    __hip_bfloat16* Vb  = (__hip_bfloat16*)p; p += NC * 2;              // 25.6 MB
    __hip_bfloat16* M   = (__hip_bfloat16*)p; p += NC * 2;              // 25.6 MB
    unsigned* rcnt  = (unsigned*)p; p += 32 * 4;
    unsigned* rcur  = (unsigned*)p; p += 32 * 4;
    unsigned* rend  = (unsigned*)p; p += 32 * 4;
    unsigned* rnext = (unsigned*)p; p += 32 * 4;
    unsigned* ucnt  = (unsigned*)p; p += (size_t)NUp * 4;   // counts -> starts
    unsigned* bsumE = (unsigned*)p; p += 1024 * 4;
    unsigned* bsumU = (unsigned*)p; p += 1024 * 4;
    int2* upair     = (int2*)p;     p += (size_t)NNZ * 8;   // (col, val) pairs
    __hip_bfloat16* WtQ = (__hip_bfloat16*)p; p += 16384 * 2;
    __hip_bfloat16* WtK = (__hip_bfloat16*)p; p += 16384 * 2;
    __hip_bfloat16* WtV = (__hip_bfloat16*)p; p += 16384 * 2;
    __hip_bfloat16* WtO = (__hip_bfloat16*)p; p += 16384 * 2;
    __hip_bfloat16* Atab = (__hip_bfloat16*)p; p += (size_t)NREL * 4096 * 2;
    __hip_bfloat16* Mtab = (__hip_bfloat16*)p; p += (size_t)NREL * 4096 * 2;

    // CSR-phase overlay inside VPh (dead until edge_pass):
    int* plocalU = (int*)VPh;            // NNZ ints
    int* plocalE = plocalU + NNZ;        // E ints

    // ---- d_out overlays (all regions fully rewritten by final kernels) ----
    float* out_ent = (float*)d_out;
    float* out_usr = out_ent + NC;
    __hip_bfloat16* embb = (__hip_bfloat16*)out_ent;                 // 25.6 MB
    __hip_bfloat16* Qb   = (__hip_bfloat16*)((char*)d_out + NC * 2); // 25.6 MB
    const long Emax = E + 512;
    float* SC   = out_usr;                                            // E*4 f32
    int4* emeta = (int4*)(out_usr + (size_t)E * 4);                   // Emax int4
    unsigned* ecnt = (unsigned*)((char*)emeta + (size_t)Emax * 16);   // N u32 (counts -> starts)

    hipMemsetAsync(rcnt, 0, (size_t)(4 * 32 * 4) + (size_t)NUp * 4, stream);  // rcnt..ucnt
    hipMemsetAsync(ecnt, 0, (size_t)N * 4, stream);

    // prep: weights, tables, emb-bf16 (streaming)
    const int nbW = 256;                               // 65536 / 256
    const int nbT = (2 * NREL * 4096 + 255) / 256;
    const int nbC = (int)((NC / 4 + 255) / 256);
    prep<<<nbW + nbT + nbC, 256, 0, stream>>>(
        W_Q, W_K, W_V, W_O, WtQ, WtK, WtV, WtO,
        att, msg, Atab, Mtab, NREL,
        emb, embb, (long)(NC / 4), nbW, nbT);

    // fused count (atomic-bound) + QKV GEMM (hidden under atomic latency)
    int gg = (N + 127) / 128;
    const int nbX = ((NNZ > E ? NNZ : E) + 255) / 256;
    qkv_count<<<nbX + 3 * gg, 256, 0, stream>>>(
        head, etyp, irow, ecnt, ucnt, rcnt, plocalE, plocalU, E, NNZ, nbX,
        embb, WtQ, WtK, WtV, Qb, Kb, Vb, N, gg);

    // hierarchical scans (wide, 3 launches)
    int nbE2 = (N + 1023) / 1024;
    int nbU2 = (NU + 1023) / 1024;
    scan_p1<<<nbE2 + nbU2, 1024, 0, stream>>>(ecnt, N, bsumE, ucnt, NU, bsumU, nbE2);
    scan_p2<<<3, 1024, 0, stream>>>(bsumE, nbE2, bsumU, nbU2, rcnt, rcur, rend, rnext, NREL);
    scan_p3<<<nbE2 + nbU2, 1024, 0, stream>>>(ecnt, N, bsumE, ucnt, NU, bsumU, nbE2);

    // fills (user pairs, rel-sorted emeta, pads) in one launch
    const int nbU = (NNZ + 255) / 256;
    const int nbE = (E + 255) / 256;
    fills<<<nbU + nbE + 1, 256, 0, stream>>>(
        irow, icol, ival, ucnt, plocalU, upair, NNZ,
        head, tail, etyp, ecnt, plocalE, rcur, emeta, E,
        rend, rnext, NREL, Emax, nbU, nbE);

    // edge + node passes (per head-pair)
    const int NWAVE = 16384;
    int chunk = (int)(((Emax + NWAVE - 1) / NWAVE + 15) & ~15L);
    edge_pass<0><<<NWAVE / 4, 256, 0, stream>>>(Qb, Kb, Vb, Atab, Mtab, emeta, SC, VPh, Emax, chunk);
    node_pass<0><<<(N + 3) / 4, 256, 0, stream>>>(SC, VPh, ecnt, M, N, E);
    edge_pass<1><<<NWAVE / 4, 256, 0, stream>>>(Qb, Kb, Vb, Atab, Mtab, emeta, SC, VPh, Emax, chunk);
    node_pass<1><<<(N + 3) / 4, 256, 0, stream>>>(SC, VPh, ecnt, M, N, E);

    // user aggregation (reads embb + upair; overwrites SC/emeta/ecnt = dead)
    user_gather<<<(NU + 7) / 8, 256, 0, stream>>>(embb, ucnt, upair, out_usr, NU, NNZ);

    // entity output GEMM last (overwrites embb+Qb region = dead)
    mfma_gemm<float><<<gg, 256, 0, stream>>>(M, WtO, out_ent, N);
}